// Round 6
// baseline (122.354 us; speedup 1.0000x reference)
//
#include <hip/hip_runtime.h>
#include <stdint.h>

#define NROWS 4096
#define DIM   512
#define TILE  128
#define NBLK  32            // NROWS / TILE
#define NPAIR 528           // NBLK*(NBLK+1)/2
#define KSTEPS 16           // DIM / 32

typedef float f32x4 __attribute__((ext_vector_type(4)));
typedef short s16x8 __attribute__((ext_vector_type(8)));

// workspace layout (bytes)
#define OFF_XB   0u
#define OFF_SQ   (NROWS * DIM * 2u)          // 4,194,304
#define OFF_LAB  (OFF_SQ + NROWS * 4u)       // + 16 KB
#define OFF_ACC  (OFF_LAB + NROWS * 4u)      // + 16 KB

__device__ __forceinline__ unsigned short f2bf(float f) {
  unsigned u = __float_as_uint(f);
  return (unsigned short)((u + 0x7FFFu + ((u >> 16) & 1u)) >> 16);
}

// ---------------- prep: fp32 -> bf16, sq rows (fp32 exact), labels -> i32, zero accum
__global__ __launch_bounds__(256) void prep_kernel(
    const float* __restrict__ X, const long long* __restrict__ lab,
    unsigned short* __restrict__ Xb, float* __restrict__ sq,
    int* __restrict__ labi, float* __restrict__ accum)
{
  int t = threadIdx.x;
  int gid = blockIdx.x * 256 + t;
  if (gid < 4) accum[gid] = 0.0f;               // sum1, sum2, cnt(bits), done-counter
  if (gid < NROWS) labi[gid] = (int)lab[gid];

  int wave = t >> 6, lane = t & 63;
  int row = blockIdx.x * 4 + wave;              // 1024 blocks * 4 rows
  const float4* Xr = (const float4*)(X + (size_t)row * DIM);
  float4 a = Xr[lane * 2];
  float4 b = Xr[lane * 2 + 1];

  uint4 pk;
  pk.x = (unsigned)f2bf(a.x) | ((unsigned)f2bf(a.y) << 16);
  pk.y = (unsigned)f2bf(a.z) | ((unsigned)f2bf(a.w) << 16);
  pk.z = (unsigned)f2bf(b.x) | ((unsigned)f2bf(b.y) << 16);
  pk.w = (unsigned)f2bf(b.z) | ((unsigned)f2bf(b.w) << 16);
  *(uint4*)(Xb + (size_t)row * DIM + lane * 8) = pk;

  float s = a.x*a.x + a.y*a.y + a.z*a.z + a.w*a.w
          + b.x*b.x + b.y*b.y + b.z*b.z + b.w*b.w;
  #pragma unroll
  for (int off = 32; off; off >>= 1) s += __shfl_down(s, off, 64);
  if (lane == 0) sq[row] = s;
}

// ---------------- main: symmetric X*X^T, NO LDS, NO BARRIERS in the main loop.
// Rounds 0-5 post-mortem: every LDS-staged variant (gl2lds / reg-staged /
// full-K, 1 or 2 barriers per K-step) lands at 40-55us with all pipes <12%
// busy -- the per-K-step 4-wave rendezvous charges the slowest wave's full
// load latency to the block, 16x per block, at only 2 blocks/CU. The operand
// reuse LDS buys is marginal anyway: Xb is 4 MB = resident in each XCD's L2.
// So each wave loads its MFMA fragments DIRECTLY global->VGPR (16B/lane
// coalesced, identical transaction shape) and runs 16 K-steps of pure
// dataflow. Zero sync until the epilogue reduce. The compiler can pipeline
// loads across K-steps with counted vmcnt (plain load->use dataflow);
// 4 waves/block cover 2x2 64x64 quadrants so L1/L2 absorb the cross-wave
// operand overlap (block step footprint 16 KB).
__global__ __launch_bounds__(256) void pair_kernel(
    const unsigned short* __restrict__ Xb, const float* __restrict__ sq,
    const int* __restrict__ labi, const float* __restrict__ marginp,
    float* __restrict__ accum, float* __restrict__ out)
{
  __shared__ float rs1[4], rs2[4];
  __shared__ int   rc[4];

  int t = threadIdx.x;

  // linear block -> (bi, bj) with bi <= bj
  int rem = blockIdx.x, bi = 0;
  while (rem >= (NBLK - bi)) { rem -= (NBLK - bi); bi++; }
  int bj = bi + rem;

  int wave = t >> 6, lane = t & 63;
  int quad = lane >> 4, ml = lane & 15;
  int rowBase = bi * TILE + (wave >> 1) * 64;   // this wave's 64x64 quadrant
  int colBase = bj * TILE + (wave & 1) * 64;

  float margin = *marginp;

  // per-lane fragment base addresses (elements):
  //   A frag r: lane(ml,quad) reads A[rowBase + r*16 + ml][kt*32 + quad*8 .. +8]
  //   B frag c: lane(ml,quad) reads B[colBase + c*16 + ml][kt*32 + quad*8 .. +8]
  const size_t aBase = (size_t)(rowBase + ml) * DIM + quad * 8;
  const size_t bBase = (size_t)(colBase + ml) * DIM + quad * 8;

  f32x4 acc[4][4] = {};

  #pragma unroll 4
  for (int kt = 0; kt < KSTEPS; ++kt) {
    const int ko = kt * 32;
    s16x8 af[4], bfr[4];
    #pragma unroll
    for (int r = 0; r < 4; ++r)
      af[r] = *(const s16x8*)(Xb + aBase + (size_t)r * 16 * DIM + ko);
    #pragma unroll
    for (int c = 0; c < 4; ++c)
      bfr[c] = *(const s16x8*)(Xb + bBase + (size_t)c * 16 * DIM + ko);
    #pragma unroll
    for (int r = 0; r < 4; ++r)
      #pragma unroll
      for (int c = 0; c < 4; ++c)
        acc[r][c] = __builtin_amdgcn_mfma_f32_16x16x32_bf16(
            af[r], bfr[c], acc[r][c], 0, 0, 0);
  }

  // ---- fused loss epilogue: sq/lab via direct (cache-hot, 16KB arrays) loads
  float s1 = 0.f, s2 = 0.f;
  int cnt = 0;
  #pragma unroll
  for (int c = 0; c < 4; ++c) {
    int col = colBase + c * 16 + ml;
    float sqc = sq[col];
    int lc = labi[col];
    #pragma unroll
    for (int r = 0; r < 4; ++r) {
      int rbase = rowBase + r * 16 + quad * 4;  // C/D layout: row=(lane>>4)*4+reg, col=lane&15
      #pragma unroll
      for (int i = 0; i < 4; ++i) {
        int row = rbase + i;
        float d = sq[row] + sqc - 2.0f * acc[r][c][i];
        d = fmaxf(d, 0.0f);
        if (labi[row] == lc) { s1 += d; cnt++; }
        else                 { s2 += fmaxf(margin - d, 0.0f); }
      }
    }
  }

  #pragma unroll
  for (int off = 32; off; off >>= 1) {
    s1  += __shfl_down(s1, off, 64);
    s2  += __shfl_down(s2, off, 64);
    cnt += __shfl_down(cnt, off, 64);
  }
  if (lane == 0) { rs1[wave] = s1; rs2[wave] = s2; rc[wave] = cnt; }
  __syncthreads();
  if (t == 0) {
    float f = (bi == bj) ? 1.f : 2.f;
    float S1 = 0.f, S2 = 0.f;
    int C = 0;
    for (int w = 0; w < 4; ++w) { S1 += rs1[w]; S2 += rs2[w]; C += rc[w]; }
    atomicAdd(&accum[0], S1 * f);
    atomicAdd(&accum[1], S2 * f);
    atomicAdd((unsigned*)accum + 2, (unsigned)C * (unsigned)((bi == bj) ? 1 : 2));
    __threadfence();
    // fused finalize: last block to finish computes the scalar output
    unsigned done = atomicAdd((unsigned*)accum + 3, 1u);
    if (done == NPAIR - 1) {
      __threadfence();
      float S1f = atomicAdd(&accum[0], 0.0f);         // device-scope coherent read
      float S2f = atomicAdd(&accum[1], 0.0f);
      unsigned c1 = atomicAdd((unsigned*)accum + 2, 0u);
      double zn1 = (double)c1;
      double zn2 = (double)NROWS * (double)NROWS - zn1;
      out[0] = (float)(0.5 * ((double)S1f / zn1 + (double)S2f / zn2));
    }
  }
}

extern "C" void kernel_launch(void* const* d_in, const int* in_sizes, int n_in,
                              void* d_out, int out_size, void* d_ws, size_t ws_size,
                              hipStream_t stream) {
  const float*     X      = (const float*)d_in[0];
  const long long* lab    = (const long long*)d_in[1];
  const float*     margin = (const float*)d_in[2];
  float*           out    = (float*)d_out;

  char* ws = (char*)d_ws;
  unsigned short* Xb   = (unsigned short*)(ws + OFF_XB);
  float*          sq   = (float*)(ws + OFF_SQ);
  int*            labi = (int*)(ws + OFF_LAB);
  float*          accum= (float*)(ws + OFF_ACC);

  prep_kernel<<<NROWS / 4, 256, 0, stream>>>(X, lab, Xb, sq, labi, accum);
  pair_kernel<<<NPAIR, 256, 0, stream>>>(Xb, sq, labi, margin, accum, out);
}